// Round 14
// baseline (202.476 us; speedup 1.0000x reference)
//
#include <hip/hip_runtime.h>
#include <math.h>

#define B_   16
#define SQ_  1024
#define SC_  1024
#define D_   768
#define H_   1536

typedef __attribute__((ext_vector_type(4))) float f32x4;
typedef __attribute__((ext_vector_type(8))) short bf16x8;

// packed f32x2 -> bf16x2 (RNE), low16 = bf16(x), high16 = bf16(y)
__device__ __forceinline__ unsigned cvtpk(float x, float y) {
  unsigned r;
  asm("v_cvt_pk_bf16_f32 %0, %1, %2" : "=v"(r) : "v"(x), "v"(y));
  return r;
}

// split float4 -> (hi bf16x4, lo bf16x4); lo = x - hi exactly representable
__device__ __forceinline__ void split4(float4 v, uint2& hi, uint2& lo) {
  unsigned h01 = cvtpk(v.x, v.y);
  unsigned h23 = cvtpk(v.z, v.w);
  float h0 = __uint_as_float(h01 << 16);
  float h1 = __uint_as_float(h01 & 0xFFFF0000u);
  float h2 = __uint_as_float(h23 << 16);
  float h3 = __uint_as_float(h23 & 0xFFFF0000u);
  hi = make_uint2(h01, h23);
  lo = make_uint2(cvtpk(v.x - h0, v.y - h1), cvtpk(v.z - h2, v.w - h3));
}

// e^s as a double, for s in ~[-300, 300]
__device__ __forceinline__ double exp_pos(float s) {
  float t = s * 1.4426950408889634f;   // s * log2(e)
  float n = floorf(t);
  float p = exp2f(t - n);              // 2^frac in [1,2)
  long long e = (long long)n;
  double scale = __longlong_as_double((unsigned long long)(e + 1023LL) << 52);
  return (double)p * scale;
}

// ---------------------------------------------------------------------------
// Kernel 0: mask compaction + workspace zeroing (folds the memsets).
// ---------------------------------------------------------------------------
__global__ __launch_bounds__(256) void compact_kernel(
    const int* __restrict__ mask_q, const int* __restrict__ mask_c,
    int* __restrict__ idx_q, int* __restrict__ idx_c, int* __restrict__ cnt,
    float* __restrict__ zeroA, int lenA, float* __restrict__ zeroB, int lenB)
{
  int which = blockIdx.x & 1;   // 0: q, 1: c
  int b     = blockIdx.x >> 1;
  const int* m = (which ? mask_c : mask_q) + b * 1024;
  int* idx     = (which ? idx_c : idx_q) + b * 1024;

  int t = threadIdx.x;
  int gid = blockIdx.x * 256 + t;            // 0 .. 8191
  for (int i = gid; i < lenA; i += 32 * 256) zeroA[i] = 0.f;
  for (int i = gid; i < lenB; i += 32 * 256) zeroB[i] = 0.f;

  __shared__ int tsum[256];
  int v[4], s = 0;
#pragma unroll
  for (int e = 0; e < 4; ++e) { v[e] = (m[t * 4 + e] != 0) ? 1 : 0; s += v[e]; }
  tsum[t] = s;
  __syncthreads();
  for (int off = 1; off < 256; off <<= 1) {
    int add = (t >= off) ? tsum[t - off] : 0;
    __syncthreads();
    tsum[t] += add;
    __syncthreads();
  }
  int pos = tsum[t] - s;   // exclusive prefix
#pragma unroll
  for (int e = 0; e < 4; ++e) {
    if (v[e]) idx[pos++] = t * 4 + e;
  }
  if (t == 255) cnt[b * 2 + which] = tsum[255];
}

// ---------------------------------------------------------------------------
// Kernel 1: ONE-WAVE-PER-BLOCK compact GEMM. Each wave owns a 64x64 tile
// (4x4 frags of 16x16x32, 48 MFMA per BK=32): no barriers (wave-private LDS),
// 16 ds_read per 48 MFMA, XOR-swizzled merged hi/lo tiles (bank-conflict-free),
// coalesced 128B-burst staging, register prefetch.
// Epilogue: S store (-inf coded) + exp-domain R/C sums (shfl + atomics).
// ---------------------------------------------------------------------------
__global__ __launch_bounds__(64) void gemm_mfma_kernel(
    const float* __restrict__ q, const float* __restrict__ c,
    const int* __restrict__ idx_q, const int* __restrict__ idx_c,
    const int* __restrict__ cnt,
    float* __restrict__ S, double* __restrict__ R, double* __restrict__ C)
{
  __shared__ unsigned short Ahl[64 * 64];   // row*64 + swizzled(hi:0-31, lo:32-63)
  __shared__ unsigned short Bhl[64 * 64];   // 16384 B total

  const int bb = blockIdx.z;
  const int i0 = blockIdx.y * 64;
  const int j0 = blockIdx.x * 64;
  const int nq = cnt[2 * bb], nc = cnt[2 * bb + 1];
  if (i0 >= nq || j0 >= nc) return;   // dead blocks exit instantly

  const int l   = threadIdx.x;        // 0..63 (single wave)
  const int fr  = l & 15;
  const int fq  = l >> 4;
  const int sr8 = l >> 3;             // 0..7 row-within-group (8 lanes/row)
  const int sc4 = (l & 7) * 4;        // float/short offset within 32-k chunk

  // gathered row base pointers for the 8 row-groups this lane stages
  const float* aP[8];
  const float* bP[8];
#pragma unroll
  for (int g = 0; g < 8; ++g) {
    int ra = idx_q[bb * 1024 + min(i0 + g * 8 + sr8, nq - 1)];
    int rb = idx_c[bb * 1024 + min(j0 + g * 8 + sr8, nc - 1)];
    aP[g] = q + ((size_t)bb * SQ_ + ra) * D_ + sc4;
    bP[g] = c + ((size_t)bb * SC_ + rb) * D_ + sc4;
  }

  f32x4 acc[4][4] = {};

  // prologue loads (coalesced: 8 lanes x 16B = 128B burst per row)
  float4 av[8], bv[8];
#pragma unroll
  for (int g = 0; g < 8; ++g) {
    av[g] = *(const float4*)(aP[g]);
    bv[g] = *(const float4*)(bP[g]);
  }

  for (int k0 = 0; k0 < D_; k0 += 32) {
    // convert + swizzled LDS store (wave-coherent: compiler orders via lgkmcnt)
#pragma unroll
    for (int g = 0; g < 8; ++g) {
      const int row = g * 8 + sr8;
      const int swz = (row & 7) << 3;
      uint2 hi, lo;
      split4(av[g], hi, lo);
      *(uint2*)&Ahl[row * 64 + (sc4 ^ swz)]        = hi;
      *(uint2*)&Ahl[row * 64 + ((32 + sc4) ^ swz)] = lo;
      split4(bv[g], hi, lo);
      *(uint2*)&Bhl[row * 64 + (sc4 ^ swz)]        = hi;
      *(uint2*)&Bhl[row * 64 + ((32 + sc4) ^ swz)] = lo;
    }

    const int nk = k0 + 32;
    if (nk < D_) {   // prefetch next k-chunk; flies under ds_read + MFMA
#pragma unroll
      for (int g = 0; g < 8; ++g) {
        av[g] = *(const float4*)(aP[g] + nk);
        bv[g] = *(const float4*)(bP[g] + nk);
      }
    }

    bf16x8 a_h[4], a_l[4], b_h[4], b_l[4];
#pragma unroll
    for (int m = 0; m < 4; ++m) {
      const int row = m * 16 + fr;
      const int swz = (row & 7) << 3;
      a_h[m] = *(const bf16x8*)&Ahl[row * 64 + ((fq * 8) ^ swz)];
      a_l[m] = *(const bf16x8*)&Ahl[row * 64 + ((32 + fq * 8) ^ swz)];
      b_h[m] = *(const bf16x8*)&Bhl[row * 64 + ((fq * 8) ^ swz)];
      b_l[m] = *(const bf16x8*)&Bhl[row * 64 + ((32 + fq * 8) ^ swz)];
    }
#pragma unroll
    for (int n = 0; n < 4; ++n)
#pragma unroll
      for (int m = 0; m < 4; ++m) {
        acc[m][n] = __builtin_amdgcn_mfma_f32_16x16x32_bf16(a_h[m], b_h[n], acc[m][n], 0, 0, 0);
        acc[m][n] = __builtin_amdgcn_mfma_f32_16x16x32_bf16(a_h[m], b_l[n], acc[m][n], 0, 0, 0);
        acc[m][n] = __builtin_amdgcn_mfma_f32_16x16x32_bf16(a_l[m], b_h[n], acc[m][n], 0, 0, 0);
      }
  }

  // ---- epilogue: S store + exp-domain R/C (shfl-only; verified in R12) ----
  double rowPart[4][4];
#pragma unroll
  for (int m = 0; m < 4; ++m)
#pragma unroll
    for (int rr = 0; rr < 4; ++rr) rowPart[m][rr] = 0.0;
  double colSum[4] = {0.0, 0.0, 0.0, 0.0};

#pragma unroll
  for (int m = 0; m < 4; ++m) {
    const int rbase = i0 + m * 16 + fq * 4;
#pragma unroll
    for (int n = 0; n < 4; ++n) {
      const int col = j0 + n * 16 + fr;
      const bool cok = (col < nc);
      float* Sp = S + ((size_t)bb * SQ_ + rbase) * SC_ + col;
#pragma unroll
      for (int rr = 0; rr < 4; ++rr) {
        float v = acc[m][n][rr];
        bool valid = ((rbase + rr) < nq) && cok && (v != 0.f);
        Sp[(size_t)rr * SC_] = valid ? v : -INFINITY;
        double e = valid ? exp_pos(v) : 0.0;
        colSum[n] += e;
        rowPart[m][rr] += e;
      }
    }
  }
#pragma unroll
  for (int m = 0; m < 4; ++m)
#pragma unroll
    for (int rr = 0; rr < 4; ++rr) {
      double x = rowPart[m][rr];
      x += __shfl_xor(x, 1); x += __shfl_xor(x, 2);
      x += __shfl_xor(x, 4); x += __shfl_xor(x, 8);
      rowPart[m][rr] = x;
    }
  if (fr == 0) {
#pragma unroll
    for (int m = 0; m < 4; ++m)
#pragma unroll
      for (int rr = 0; rr < 4; ++rr) {
        double x = rowPart[m][rr];
        if (x != 0.0) atomicAdd(&R[bb * SQ_ + i0 + m * 16 + fq * 4 + rr], x);
      }
  }
#pragma unroll
  for (int n = 0; n < 4; ++n) {
    double x = colSum[n];
    x += __shfl_xor(x, 16); x += __shfl_xor(x, 32);
    if (fq == 0 && x != 0.0) {
      int col = j0 + n * 16 + fr;
      if (col < nc) atomicAdd(&C[bb * SC_ + col], x);
    }
  }
}

// ---------------------------------------------------------------------------
// Kernel 2: single pass over S -> cp[j] = sum_i e^{s-lnR_i} and
// rpp[i] = sum_j e^{s-lnC_j}. 64-col strip per block, 16 waves over rows.
// ---------------------------------------------------------------------------
__global__ __launch_bounds__(1024) void pass2_kernel(
    const float* __restrict__ S, const int* __restrict__ cnt,
    const double* __restrict__ R, const double* __restrict__ C,
    float* __restrict__ cp, float* __restrict__ rpp)
{
  __shared__ float lnR_lds[SQ_];
  __shared__ float red[16][64];

  int b  = blockIdx.y;
  int j0 = blockIdx.x * 64;
  int nq_pad = (cnt[2 * b] + 63) & ~63;
  int nc_pad = (cnt[2 * b + 1] + 63) & ~63;
  if (j0 >= nc_pad) return;        // block-uniform exit before barriers
  int t = threadIdx.x;

  if (t < nq_pad) {
    double Ri = R[b * SQ_ + t];
    lnR_lds[t] = (Ri > 0.0) ? (float)log(Ri) : INFINITY;
  }
  __syncthreads();

  int lane = t & 63, wv = t >> 6;
  int j = j0 + lane;
  double Cj = C[b * SC_ + j];
  float lnCj = (Cj > 0.0) ? (float)log(Cj) : INFINITY;

  int chunk = nq_pad >> 4;          // rows per wave
  int i0 = wv * chunk;
  const float* Sb = S + ((size_t)b * SQ_ + i0) * SC_ + j;

  float cpAcc = 0.f;
  for (int ii = 0; ii < chunk; ++ii) {
    int i = i0 + ii;
    float v = Sb[(size_t)ii * SC_];
    cpAcc += __expf(v - lnR_lds[i]);
    float e2 = __expf(v - lnCj);
#pragma unroll
    for (int o = 32; o; o >>= 1) e2 += __shfl_xor(e2, o);
    if (lane == 0) atomicAdd(&rpp[b * SQ_ + i], e2);
  }

  red[wv][lane] = cpAcc;
  __syncthreads();
  if (t < 64) {
    float s = 0.f;
#pragma unroll
    for (int k = 0; k < 16; ++k) s += red[k][t];
    cp[b * SC_ + j0 + t] = s;
  }
}

// ---------------------------------------------------------------------------
// Kernel 3: combine partials over VALID rows via idx gather; atomicAdd into X.
// ---------------------------------------------------------------------------
__global__ __launch_bounds__(256) void combine_kernel(
    const float* __restrict__ q, const float* __restrict__ c,
    const int* __restrict__ idx_q, const int* __restrict__ idx_c,
    const int* __restrict__ cnt,
    const float* __restrict__ cp, const float* __restrict__ rpp,
    float* __restrict__ X)
{
  int jc = blockIdx.x;   // 0..31
  int op = blockIdx.y;   // 0: c/cp ; 1: q/rpp
  int b  = blockIdx.z;
  int t  = threadIdx.x;

  int n = op ? cnt[2 * b] : cnt[2 * b + 1];
  const float* src = op ? (q + (size_t)b * SQ_ * D_) : (c + (size_t)b * SC_ * D_);
  const float* wv  = op ? (rpp + b * SQ_) : (cp + b * SC_);
  const int*   idx = (op ? idx_q : idx_c) + b * 1024;

  float a0 = 0.f, a1 = 0.f, a2 = 0.f;
  int je = min(jc * 32 + 32, n);
  for (int j = jc * 32; j < je; ++j) {
    float wj = wv[j];
    const float* r = src + (size_t)idx[j] * D_;
    a0 += wj * r[t];
    a1 += wj * r[t + 256];
    a2 += wj * r[t + 512];
  }
  float* xp = X + (size_t)b * H_ + op * D_;
  atomicAdd(&xp[t], a0);
  atomicAdd(&xp[t + 256], a1);
  atomicAdd(&xp[t + 512], a2);
}

// ---------------------------------------------------------------------------
// Kernel 4: fc1. One wave per h; W1 row in registers, loop over 16 batches.
// ---------------------------------------------------------------------------
__global__ __launch_bounds__(256) void fc1_kernel(
    const float* __restrict__ X, const float* __restrict__ W1,
    const float* __restrict__ b1, float* __restrict__ Y)
{
  int w = threadIdx.x >> 6, lane = threadIdx.x & 63;
  int h = blockIdx.x * 4 + w;           // 0..1535
  const float4* wr = (const float4*)(W1 + (size_t)h * H_);
  float4 wv[6];
#pragma unroll
  for (int it = 0; it < 6; ++it) wv[it] = wr[it * 64 + lane];
  float bias = b1[h];

  for (int b = 0; b < B_; ++b) {
    const float4* x = (const float4*)(X + (size_t)b * H_);
    float accv = 0.f;
#pragma unroll
    for (int it = 0; it < 6; ++it) {
      float4 xv = x[it * 64 + lane];
      accv += xv.x * wv[it].x + xv.y * wv[it].y + xv.z * wv[it].z + xv.w * wv[it].w;
    }
#pragma unroll
    for (int o = 32; o; o >>= 1) accv += __shfl_xor(accv, o);
    if (lane == 0) Y[(size_t)b * H_ + h] = tanhf(accv + bias);
  }
}

// ---------------------------------------------------------------------------
// Kernel 5: fc2 + log_softmax + NLL loss.
// ---------------------------------------------------------------------------
__global__ __launch_bounds__(64) void fc2_loss_kernel(
    const float* __restrict__ Y, const float* __restrict__ W2,
    const float* __restrict__ b2, const int* __restrict__ labels,
    float* __restrict__ out)
{
  __shared__ float logp_s[B_][2];
  int t = threadIdx.x;
  if (t < 2 * B_) {
    int b = t >> 1, n = t & 1;
    const float* y = Y + (size_t)b * H_;
    const float* w = W2 + (size_t)n * H_;
    float accv = b2[n];
    for (int k = 0; k < H_; ++k) accv += y[k] * w[k];
    logp_s[b][n] = accv;
  }
  __syncthreads();
  if (t < B_) {
    float l0 = logp_s[t][0], l1 = logp_s[t][1];
    float m = fmaxf(l0, l1);
    float lse = m + logf(expf(l0 - m) + expf(l1 - m));
    logp_s[t][0] = l0 - lse;
    logp_s[t][1] = l1 - lse;
  }
  __syncthreads();
  if (t < 2 * B_) out[1 + t] = logp_s[t >> 1][t & 1];
  if (t == 0) {
    float loss = 0.f;
    for (int b = 0; b < B_; ++b) loss -= logp_s[b][labels[b]];
    out[0] = loss / (float)B_;
  }
}

// ---------------------------------------------------------------------------
extern "C" void kernel_launch(void* const* d_in, const int* in_sizes, int n_in,
                              void* d_out, int out_size, void* d_ws, size_t ws_size,
                              hipStream_t stream) {
  const float* q      = (const float*)d_in[0];
  const float* c      = (const float*)d_in[1];
  const int*   mask_q = (const int*)d_in[2];
  const int*   mask_c = (const int*)d_in[3];
  const int*   labels = (const int*)d_in[4];
  const float* W1     = (const float*)d_in[5];
  const float* b1     = (const float*)d_in[6];
  const float* W2     = (const float*)d_in[7];
  const float* b2     = (const float*)d_in[8];
  float* out = (float*)d_out;

  float*  ws    = (float*)d_ws;
  float*  S     = ws;                                     // 16M floats (64 MiB)
  double* R     = (double*)(ws + (size_t)B_ * SQ_ * SC_); // 16K doubles
  double* C     = R + B_ * SQ_;                           // 16K doubles
  float*  cp    = (float*)(C + B_ * SC_);                 // 16K floats
  float*  rpp   = cp + B_ * SC_;                          // 16K floats
  int*    cnt   = (int*)(rpp + B_ * SQ_);                 // 32 ints
  int*    idx_q = cnt + 2 * B_;                           // 16K ints
  int*    idx_c = idx_q + B_ * SQ_;                       // 16K ints
  float*  X     = (float*)(idx_c + B_ * SC_);             // 16*1536
  float*  Y     = X + B_ * H_;                            // 16*1536
  float*  zeroA = (float*)R;
  const int lenA = 2 * B_ * SQ_ * 2 + 2 * B_ * SC_;       // 98304 float-slots
  const int lenB = B_ * H_;                               // 24576 (X)

  compact_kernel<<<2 * B_, 256, 0, stream>>>(mask_q, mask_c, idx_q, idx_c, cnt,
                                             zeroA, lenA, X, lenB);

  dim3 g1(SC_ / 64, SQ_ / 64, B_);
  gemm_mfma_kernel<<<g1, 64, 0, stream>>>(q, c, idx_q, idx_c, cnt, S, R, C);

  pass2_kernel<<<dim3(SC_ / 64, B_), 1024, 0, stream>>>(S, cnt, R, C, cp, rpp);

  combine_kernel<<<dim3(32, 2, B_), 256, 0, stream>>>(q, c, idx_q, idx_c, cnt,
                                                      cp, rpp, X);
  fc1_kernel<<<H_ / 4, 256, 0, stream>>>(X, W1, b1, Y);
  fc2_loss_kernel<<<1, 64, 0, stream>>>(Y, W2, b2, labels, out);
}

// Round 15
// 167.368 us; speedup vs baseline: 1.2098x; 1.2098x over previous
//
#include <hip/hip_runtime.h>
#include <math.h>

#define B_   16
#define SQ_  1024
#define SC_  1024
#define D_   768
#define H_   1536

typedef __attribute__((ext_vector_type(4))) float f32x4;
typedef __attribute__((ext_vector_type(8))) short bf16x8;

// packed f32x2 -> bf16x2 (RNE), low16 = bf16(x), high16 = bf16(y)
__device__ __forceinline__ unsigned cvtpk(float x, float y) {
  unsigned r;
  asm("v_cvt_pk_bf16_f32 %0, %1, %2" : "=v"(r) : "v"(x), "v"(y));
  return r;
}

// split float4 -> (hi bf16x4, lo bf16x4); lo = x - hi exactly representable
__device__ __forceinline__ void split4(float4 v, uint2& hi, uint2& lo) {
  unsigned h01 = cvtpk(v.x, v.y);
  unsigned h23 = cvtpk(v.z, v.w);
  float h0 = __uint_as_float(h01 << 16);
  float h1 = __uint_as_float(h01 & 0xFFFF0000u);
  float h2 = __uint_as_float(h23 << 16);
  float h3 = __uint_as_float(h23 & 0xFFFF0000u);
  hi = make_uint2(h01, h23);
  lo = make_uint2(cvtpk(v.x - h0, v.y - h1), cvtpk(v.z - h2, v.w - h3));
}

// ---------------------------------------------------------------------------
// Kernel 0: mask compaction + zero X (folds memset).
// ---------------------------------------------------------------------------
__global__ __launch_bounds__(256) void compact_kernel(
    const int* __restrict__ mask_q, const int* __restrict__ mask_c,
    int* __restrict__ idx_q, int* __restrict__ idx_c, int* __restrict__ cnt,
    float* __restrict__ zeroB, int lenB)
{
  int which = blockIdx.x & 1;   // 0: q, 1: c
  int b     = blockIdx.x >> 1;
  const int* m = (which ? mask_c : mask_q) + b * 1024;
  int* idx     = (which ? idx_c : idx_q) + b * 1024;

  int t = threadIdx.x;
  int gid = blockIdx.x * 256 + t;            // 0 .. 8191
  for (int i = gid; i < lenB; i += 32 * 256) zeroB[i] = 0.f;

  __shared__ int tsum[256];
  int v[4], s = 0;
#pragma unroll
  for (int e = 0; e < 4; ++e) { v[e] = (m[t * 4 + e] != 0) ? 1 : 0; s += v[e]; }
  tsum[t] = s;
  __syncthreads();
  for (int off = 1; off < 256; off <<= 1) {
    int add = (t >= off) ? tsum[t - off] : 0;
    __syncthreads();
    tsum[t] += add;
    __syncthreads();
  }
  int pos = tsum[t] - s;   // exclusive prefix
#pragma unroll
  for (int e = 0; e < 4; ++e) {
    if (v[e]) idx[pos++] = t * 4 + e;
  }
  if (t == 255) cnt[b * 2 + which] = tsum[255];
}

// ---------------------------------------------------------------------------
// Kernel 1: compact GEMM. R8 structure (64x64 tile, 4 waves, BK=32, dbuf,
// register prefetch, ONE barrier/iter) + merged hi/lo XOR-swizzled LDS:
// 32 KB LDS (5 blocks/CU) and conflict-free frag reads.
// Layout per matrix/buffer: row*64 + (col ^ ((row&7)<<3)), hi cols 0-31,
// lo cols 32-63 (XOR is bijective; write & read use identical formula).
// ---------------------------------------------------------------------------
__global__ __launch_bounds__(256) void gemm_mfma_kernel(
    const float* __restrict__ q, const float* __restrict__ c,
    const int* __restrict__ idx_q, const int* __restrict__ idx_c,
    const int* __restrict__ cnt, float* __restrict__ S)
{
  __shared__ unsigned short Ahl[2][64 * 64];
  __shared__ unsigned short Bhl[2][64 * 64];   // 32768 B total

  const int bb = blockIdx.z;
  const int i0 = blockIdx.y * 64;
  const int j0 = blockIdx.x * 64;
  const int nq = cnt[2 * bb], nc = cnt[2 * bb + 1];
  if (i0 >= nq || j0 >= nc) return;   // block-uniform exit (before barriers)

  const int t    = threadIdx.x;
  const int lane = t & 63;
  const int w    = t >> 6;            // 0..3 = n-frag
  const int srow = t >> 2;            // 0..63 staging row
  const int sc8  = (t & 3) * 8;       // 8 contiguous k-floats (32B/lane)
  const int swzS = (srow & 7) << 3;
  const int fr   = lane & 15;
  const int fq   = lane >> 4;

  const int rq = idx_q[bb * 1024 + min(i0 + srow, nq - 1)];
  const int rc = idx_c[bb * 1024 + min(j0 + srow, nc - 1)];
  const float* qrowP = q + ((size_t)bb * SQ_ + rq) * D_ + sc8;
  const float* crowP = c + ((size_t)bb * SC_ + rc) * D_ + sc8;

  f32x4 acc[4] = {};

  // prologue: load + convert + store k-tile 0 into buf 0
  float4 a0 = *(const float4*)(qrowP);
  float4 a1 = *(const float4*)(qrowP + 4);
  float4 b0 = *(const float4*)(crowP);
  float4 b1 = *(const float4*)(crowP + 4);
  {
    uint2 hi, lo;
    split4(a0, hi, lo);
    *(uint2*)&Ahl[0][srow * 64 + ((sc8 + 0) ^ swzS)]      = hi;
    *(uint2*)&Ahl[0][srow * 64 + ((32 + sc8 + 0) ^ swzS)] = lo;
    split4(a1, hi, lo);
    *(uint2*)&Ahl[0][srow * 64 + ((sc8 + 4) ^ swzS)]      = hi;
    *(uint2*)&Ahl[0][srow * 64 + ((32 + sc8 + 4) ^ swzS)] = lo;
    split4(b0, hi, lo);
    *(uint2*)&Bhl[0][srow * 64 + ((sc8 + 0) ^ swzS)]      = hi;
    *(uint2*)&Bhl[0][srow * 64 + ((32 + sc8 + 0) ^ swzS)] = lo;
    split4(b1, hi, lo);
    *(uint2*)&Bhl[0][srow * 64 + ((sc8 + 4) ^ swzS)]      = hi;
    *(uint2*)&Bhl[0][srow * 64 + ((32 + sc8 + 4) ^ swzS)] = lo;
  }
  __syncthreads();

  int cur = 0;
  for (int k0 = 0; k0 < D_; k0 += 32) {
    const int next = k0 + 32;
    const bool has_next = (next < D_);
    if (has_next) {   // issue next tile's loads early; fly under MFMA
      a0 = *(const float4*)(qrowP + next);
      a1 = *(const float4*)(qrowP + next + 4);
      b0 = *(const float4*)(crowP + next);
      b1 = *(const float4*)(crowP + next + 4);
    }

    bf16x8 b_h, b_l;
    {
      const int row = w * 16 + fr;
      const int sw  = (row & 7) << 3;
      b_h = *(const bf16x8*)&Bhl[cur][row * 64 + ((fq * 8) ^ sw)];
      b_l = *(const bf16x8*)&Bhl[cur][row * 64 + ((32 + fq * 8) ^ sw)];
    }
#pragma unroll
    for (int m = 0; m < 4; ++m) {
      const int row = m * 16 + fr;
      const int sw  = (row & 7) << 3;
      bf16x8 a_h = *(const bf16x8*)&Ahl[cur][row * 64 + ((fq * 8) ^ sw)];
      bf16x8 a_l = *(const bf16x8*)&Ahl[cur][row * 64 + ((32 + fq * 8) ^ sw)];
      acc[m] = __builtin_amdgcn_mfma_f32_16x16x32_bf16(a_h, b_h, acc[m], 0, 0, 0);
      acc[m] = __builtin_amdgcn_mfma_f32_16x16x32_bf16(a_h, b_l, acc[m], 0, 0, 0);
      acc[m] = __builtin_amdgcn_mfma_f32_16x16x32_bf16(a_l, b_h, acc[m], 0, 0, 0);
    }

    if (has_next) {   // convert + store into the OTHER buffer (no conflict)
      const int nxt = cur ^ 1;
      uint2 hi, lo;
      split4(a0, hi, lo);
      *(uint2*)&Ahl[nxt][srow * 64 + ((sc8 + 0) ^ swzS)]      = hi;
      *(uint2*)&Ahl[nxt][srow * 64 + ((32 + sc8 + 0) ^ swzS)] = lo;
      split4(a1, hi, lo);
      *(uint2*)&Ahl[nxt][srow * 64 + ((sc8 + 4) ^ swzS)]      = hi;
      *(uint2*)&Ahl[nxt][srow * 64 + ((32 + sc8 + 4) ^ swzS)] = lo;
      split4(b0, hi, lo);
      *(uint2*)&Bhl[nxt][srow * 64 + ((sc8 + 0) ^ swzS)]      = hi;
      *(uint2*)&Bhl[nxt][srow * 64 + ((32 + sc8 + 0) ^ swzS)] = lo;
      split4(b1, hi, lo);
      *(uint2*)&Bhl[nxt][srow * 64 + ((sc8 + 4) ^ swzS)]      = hi;
      *(uint2*)&Bhl[nxt][srow * 64 + ((32 + sc8 + 4) ^ swzS)] = lo;
    }
    __syncthreads();   // single barrier per iteration
    cur ^= 1;
  }

  // epilogue: C/D layout col=lane&15, row=(lane>>4)*4+reg (+16 per m-frag)
  const int col = j0 + w * 16 + fr;
  const bool cok = (col < nc);
#pragma unroll
  for (int m = 0; m < 4; ++m) {
    int rbase = i0 + m * 16 + fq * 4;
    float* Sp = S + ((size_t)bb * SQ_ + rbase) * SC_ + col;
#pragma unroll
    for (int rr = 0; rr < 4; ++rr) {
      float v = acc[m][rr];
      bool valid = ((rbase + rr) < nq) && cok && (v != 0.f);
      Sp[(size_t)rr * SC_] = valid ? v : -INFINITY;
    }
  }
}

// ---------------------------------------------------------------------------
// Kernel 2: per-row online (max, sum exp); writes ENCODED stats:
// rmE = +inf (dead) else rowmax ; riE = 0 (dead) else 1/rowsum.
// ---------------------------------------------------------------------------
__global__ __launch_bounds__(256) void row_stats_kernel(
    const float* __restrict__ S, const int* __restrict__ cnt,
    float* __restrict__ rmE, float* __restrict__ riE)
{
  int w    = threadIdx.x >> 6;
  int lane = threadIdx.x & 63;
  int row  = blockIdx.x * 4 + w;   // b*SQ_ + i
  int b = row >> 10, i = row & 1023;
  int nq_pad = (cnt[2 * b] + 63) & ~63;
  if (i >= nq_pad) return;         // wave-uniform, no barriers in kernel
  int nc_pad = (cnt[2 * b + 1] + 63) & ~63;
  const float4* Sr = (const float4*)(S + (size_t)row * SC_);

  float m = -INFINITY, s = 0.f;
  int n4 = nc_pad >> 2;            // float4 count (multiple of 16)
  for (int j4 = lane; j4 < n4; j4 += 64) {
    float4 v = Sr[j4];
    float vm = fmaxf(fmaxf(v.x, v.y), fmaxf(v.z, v.w));
    if (vm > m) { s *= __expf(m - vm); m = vm; }
    if (m > -INFINITY) {
      s += __expf(v.x - m) + __expf(v.y - m) + __expf(v.z - m) + __expf(v.w - m);
    }
  }
#pragma unroll
  for (int o = 32; o; o >>= 1) {
    float om = __shfl_xor(m, o);
    float os = __shfl_xor(s, o);
    float nm = fmaxf(m, om);
    float e1 = (m == nm) ? 1.f : __expf(m - nm);
    float e2 = (om == nm) ? 1.f : __expf(om - nm);
    s = s * e1 + os * e2;
    m = nm;
  }
  if (lane == 0) {
    bool dead = !(s > 0.f);
    rmE[row] = dead ? INFINITY : m;
    riE[row] = dead ? 0.f : 1.0f / s;
  }
}

// ---------------------------------------------------------------------------
// Kernel 3: fused column pass -> encoded cmE/ciE AND colsum_p in one S read.
// 1024 threads: 16 waves each own nq_pad/16 rows; LDS merge. Grid (16, B).
// ---------------------------------------------------------------------------
__global__ __launch_bounds__(1024) void col_pass_kernel(
    const float* __restrict__ S, const int* __restrict__ cnt,
    const float* __restrict__ rmE, const float* __restrict__ riE,
    float* __restrict__ cmE, float* __restrict__ ciE,
    float* __restrict__ colsum_p)
{
  __shared__ float redm[1024], reds[1024], redp[1024];

  int b  = blockIdx.y;
  int j0 = blockIdx.x * 64;
  int nq_pad = (cnt[2 * b] + 63) & ~63;
  int nc_pad = (cnt[2 * b + 1] + 63) & ~63;
  if (j0 >= nc_pad) return;        // block-uniform exit before barriers
  int t  = threadIdx.x;

  int j     = j0 + (t & 63);
  int wv    = t >> 6;                        // 0..15
  int chunk = nq_pad >> 4;                   // rows per wave (mult of 4)
  int i0    = wv * chunk;
  const float* Sb  = S + ((size_t)b * SQ_ + i0) * SC_ + j;
  const float* rmb = rmE + b * SQ_ + i0;
  const float* rib = riE + b * SQ_ + i0;

  float cm = -INFINITY, cs = 0.f, cp = 0.f;
  for (int ii = 0; ii < chunk; ++ii) {
    float v = Sb[(size_t)ii * SC_];
    cp += __expf(v - rmb[ii]) * rib[ii];
    if (v > cm) { cs = cs * __expf(cm - v) + 1.0f; cm = v; }
    else if (cm > -INFINITY) cs += __expf(v - cm);
  }

  redm[t] = cm; reds[t] = cs; redp[t] = cp;
  __syncthreads();
  if (t < 64) {
    float m = redm[t], s = reds[t], p = redp[t];
#pragma unroll
    for (int wv2 = 1; wv2 < 16; ++wv2) {
      float om = redm[wv2 * 64 + t], os = reds[wv2 * 64 + t];
      float nm = fmaxf(m, om);
      float e1 = (m == nm) ? 1.f : __expf(m - nm);
      float e2 = (om == nm) ? 1.f : __expf(om - nm);
      s = s * e1 + os * e2; m = nm;
      p += redp[wv2 * 64 + t];
    }
    bool dead = !(s > 0.f);
    cmE[b * SC_ + j0 + t] = dead ? INFINITY : m;
    ciE[b * SC_ + j0 + t] = dead ? 0.f : 1.0f / s;
    colsum_p[b * SC_ + j0 + t] = p;
  }
}

// ---------------------------------------------------------------------------
// Kernel 4: rowsum_pp[b,i] = sum_j exp(S - cmE_j) * ciE_j. Pure streaming.
// ---------------------------------------------------------------------------
__global__ __launch_bounds__(256) void rowsum_pp_kernel(
    const float* __restrict__ S, const int* __restrict__ cnt,
    const float* __restrict__ cmE, const float* __restrict__ ciE,
    float* __restrict__ rowsum_pp)
{
  int t = threadIdx.x;
  int row0 = blockIdx.x * 4;        // 4 rows per block, same b
  int b = row0 >> 10;
  int nq = cnt[2 * b];
  if ((row0 & 1023) >= nq) return;
  int nc_pad = (cnt[2 * b + 1] + 63) & ~63;

  int w = t >> 6, lane = t & 63;
  int row = row0 + w;
  const float4* Sr  = (const float4*)(S + (size_t)row * SC_);
  const float4* cm4 = (const float4*)(cmE + b * SC_);
  const float4* ci4 = (const float4*)(ciE + b * SC_);

  float accv = 0.f;
  int n4 = nc_pad >> 2;             // float4 count (multiple of 16)
  for (int j4 = lane; j4 < n4; j4 += 64) {
    float4 v = Sr[j4];
    float4 cm = cm4[j4];
    float4 ci = ci4[j4];
    accv += __expf(v.x - cm.x) * ci.x;
    accv += __expf(v.y - cm.y) * ci.y;
    accv += __expf(v.z - cm.z) * ci.z;
    accv += __expf(v.w - cm.w) * ci.w;
  }
#pragma unroll
  for (int o = 32; o; o >>= 1) accv += __shfl_xor(accv, o);
  if (lane == 0) rowsum_pp[row] = accv;
}

// ---------------------------------------------------------------------------
// Kernel 5: combine partials over VALID rows via idx gather; atomicAdd into X
// (X pre-zeroed by compact_kernel).
// ---------------------------------------------------------------------------
__global__ __launch_bounds__(256) void combine_kernel(
    const float* __restrict__ q, const float* __restrict__ c,
    const int* __restrict__ idx_q, const int* __restrict__ idx_c,
    const int* __restrict__ cnt,
    const float* __restrict__ cp, const float* __restrict__ rpp,
    float* __restrict__ X)
{
  int jc = blockIdx.x;   // 0..31
  int op = blockIdx.y;   // 0: c/cp ; 1: q/rpp
  int b  = blockIdx.z;
  int t  = threadIdx.x;

  int n = op ? cnt[2 * b] : cnt[2 * b + 1];
  const float* src = op ? (q + (size_t)b * SQ_ * D_) : (c + (size_t)b * SC_ * D_);
  const float* wv  = op ? (rpp + b * SQ_) : (cp + b * SC_);
  const int*   idx = (op ? idx_q : idx_c) + b * 1024;

  float a0 = 0.f, a1 = 0.f, a2 = 0.f;
  int je = min(jc * 32 + 32, n);
  for (int j = jc * 32; j < je; ++j) {
    float wj = wv[j];
    const float* r = src + (size_t)idx[j] * D_;
    a0 += wj * r[t];
    a1 += wj * r[t + 256];
    a2 += wj * r[t + 512];
  }
  float* xp = X + (size_t)b * H_ + op * D_;
  atomicAdd(&xp[t], a0);
  atomicAdd(&xp[t + 256], a1);
  atomicAdd(&xp[t + 512], a2);
}

// ---------------------------------------------------------------------------
// Kernel 6: fc1. One wave per h; W1 row in registers, loop over 16 batches.
// ---------------------------------------------------------------------------
__global__ __launch_bounds__(256) void fc1_kernel(
    const float* __restrict__ X, const float* __restrict__ W1,
    const float* __restrict__ b1, float* __restrict__ Y)
{
  int w = threadIdx.x >> 6, lane = threadIdx.x & 63;
  int h = blockIdx.x * 4 + w;           // 0..1535
  const float4* wr = (const float4*)(W1 + (size_t)h * H_);
  float4 wv[6];
#pragma unroll
  for (int it = 0; it < 6; ++it) wv[it] = wr[it * 64 + lane];
  float bias = b1[h];

  for (int b = 0; b < B_; ++b) {
    const float4* x = (const float4*)(X + (size_t)b * H_);
    float accv = 0.f;
#pragma unroll
    for (int it = 0; it < 6; ++it) {
      float4 xv = x[it * 64 + lane];
      accv += xv.x * wv[it].x + xv.y * wv[it].y + xv.z * wv[it].z + xv.w * wv[it].w;
    }
#pragma unroll
    for (int o = 32; o; o >>= 1) accv += __shfl_xor(accv, o);
    if (lane == 0) Y[(size_t)b * H_ + h] = tanhf(accv + bias);
  }
}

// ---------------------------------------------------------------------------
// Kernel 7: fc2 + log_softmax + NLL loss.
// ---------------------------------------------------------------------------
__global__ __launch_bounds__(64) void fc2_loss_kernel(
    const float* __restrict__ Y, const float* __restrict__ W2,
    const float* __restrict__ b2, const int* __restrict__ labels,
    float* __restrict__ out)
{
  __shared__ float logp_s[B_][2];
  int t = threadIdx.x;
  if (t < 2 * B_) {
    int b = t >> 1, n = t & 1;
    const float* y = Y + (size_t)b * H_;
    const float* w = W2 + (size_t)n * H_;
    float accv = b2[n];
    for (int k = 0; k < H_; ++k) accv += y[k] * w[k];
    logp_s[b][n] = accv;
  }
  __syncthreads();
  if (t < B_) {
    float l0 = logp_s[t][0], l1 = logp_s[t][1];
    float m = fmaxf(l0, l1);
    float lse = m + logf(expf(l0 - m) + expf(l1 - m));
    logp_s[t][0] = l0 - lse;
    logp_s[t][1] = l1 - lse;
  }
  __syncthreads();
  if (t < 2 * B_) out[1 + t] = logp_s[t >> 1][t & 1];
  if (t == 0) {
    float loss = 0.f;
    for (int b = 0; b < B_; ++b) loss -= logp_s[b][labels[b]];
    out[0] = loss / (float)B_;
  }
}

// ---------------------------------------------------------------------------
extern "C" void kernel_launch(void* const* d_in, const int* in_sizes, int n_in,
                              void* d_out, int out_size, void* d_ws, size_t ws_size,
                              hipStream_t stream) {
  const float* q      = (const float*)d_in[0];
  const float* c      = (const float*)d_in[1];
  const int*   mask_q = (const int*)d_in[2];
  const int*   mask_c = (const int*)d_in[3];
  const int*   labels = (const int*)d_in[4];
  const float* W1     = (const float*)d_in[5];
  const float* b1     = (const float*)d_in[6];
  const float* W2     = (const float*)d_in[7];
  const float* b2     = (const float*)d_in[8];
  float* out = (float*)d_out;

  float*  ws    = (float*)d_ws;
  float*  S     = ws;                                  // 16M floats (64 MiB)
  float*  rmE   = ws + (size_t)B_ * SQ_ * SC_;         // 16K
  float*  riE   = rmE + B_ * SQ_;                      // 16K
  float*  cmE   = riE + B_ * SQ_;                      // 16K
  float*  ciE   = cmE + B_ * SC_;                      // 16K
  float*  cp    = ciE + B_ * SC_;                      // 16K (colsum_p)
  float*  rpp   = cp + B_ * SC_;                       // 16K (rowsum_pp)
  int*    cnt   = (int*)(rpp + B_ * SQ_);              // 32 ints
  int*    idx_q = cnt + 2 * B_;                        // 16K ints
  int*    idx_c = idx_q + B_ * SQ_;                    // 16K ints
  float*  X     = (float*)(idx_c + B_ * SC_);          // 16*1536
  float*  Y     = X + B_ * H_;                         // 16*1536
  const int lenB = B_ * H_;                            // 24576 (X)

  compact_kernel<<<2 * B_, 256, 0, stream>>>(mask_q, mask_c, idx_q, idx_c, cnt,
                                             X, lenB);

  dim3 g1(SC_ / 64, SQ_ / 64, B_);
  gemm_mfma_kernel<<<g1, 256, 0, stream>>>(q, c, idx_q, idx_c, cnt, S);

  row_stats_kernel<<<(B_ * SQ_) / 4, 256, 0, stream>>>(S, cnt, rmE, riE);
  col_pass_kernel<<<dim3(SC_ / 64, B_), 1024, 0, stream>>>(S, cnt, rmE, riE,
                                                           cmE, ciE, cp);
  rowsum_pp_kernel<<<(B_ * SQ_) / 4, 256, 0, stream>>>(S, cnt, cmE, ciE, rpp);

  combine_kernel<<<dim3(32, 2, B_), 256, 0, stream>>>(q, c, idx_q, idx_c, cnt,
                                                      cp, rpp, X);
  fc1_kernel<<<H_ / 4, 256, 0, stream>>>(X, W1, b1, Y);
  fc2_loss_kernel<<<1, 64, 0, stream>>>(Y, W2, b2, labels, out);
}